// Round 26
// baseline (108.162 us; speedup 1.0000x reference)
//
#include <hip/hip_runtime.h>

typedef __attribute__((ext_vector_type(8))) short short8;
typedef __attribute__((ext_vector_type(4))) float f32x4;
typedef __attribute__((ext_vector_type(16))) float f32x16;

__device__ __forceinline__ unsigned short f2bf(float f) {
    unsigned u = __builtin_bit_cast(unsigned, f);
    u += 0x7FFFu + ((u >> 16) & 1u);
    return (unsigned short)(u >> 16);
}
__device__ __forceinline__ short8 ld_frag(const uint4* p, size_t idx16) {
    return __builtin_bit_cast(short8, p[idx16]);
}
__device__ __forceinline__ unsigned cvt_pk_bf16(float lo, float hi) {
    unsigned r;
    asm("v_cvt_pk_bf16_f32 %0, %1, %2" : "=v"(r) : "v"(lo), "v"(hi));
    return r;
}
// async global->LDS, 16B per lane; lds base must be wave-uniform (HW adds lane*16)
__device__ __forceinline__ void gload_lds16(const void* g, void* l) {
    __builtin_amdgcn_global_load_lds((const __attribute__((address_space(1))) void*)g,
                                     (__attribute__((address_space(3))) void*)l, 16, 0, 0);
}

// ---------------- prep: rope table + cast x + both weight transposes, one launch ----------------
__global__ __launch_bounds__(256) void prep_kernel(const float* __restrict__ x, unsigned short* __restrict__ xb,
                                                   const float* __restrict__ wqkv, unsigned short* __restrict__ wqkvT,
                                                   const float* __restrict__ wout, unsigned short* __restrict__ woutT,
                                                   float* __restrict__ cosT, float* __restrict__ sinT) {
    __shared__ float t[32][33];
    int bid = blockIdx.x, tid = threadIdx.x;
    if (bid < 256) {                       // rope table: [2048][32]
        int idx = bid * 256 + tid;
        int s = idx >> 5, i = idx & 31;
        // inv_freq = 10000^(-i/32) = 2^(-i*log2(10000)/32); log2(10000)=13.28771238
        float inv = exp2f(-(float)i * (13.28771238f / 32.f));
        float ang = (float)s * inv;
        cosT[idx] = cosf(ang);
        sinT[idx] = sinf(ang);
        return;
    }
    if (bid < 4352) {                      // cast x -> bf16, 4 elems/thread
        int i = (bid - 256) * 256 + tid;
        float4 v = reinterpret_cast<const float4*>(x)[i];
        ushort4 o;
        o.x = f2bf(v.x); o.y = f2bf(v.y); o.z = f2bf(v.z); o.w = f2bf(v.w);
        reinterpret_cast<ushort4*>(xb)[i] = o;
        return;
    }
    const float* in; unsigned short* out; int R, C, c0, r0;
    if (bid < 7424) {                      // transpose wqkv [1024][3072] -> [3072][1024]
        int b2 = bid - 4352;
        in = wqkv; out = wqkvT; R = 1024; C = 3072;
        c0 = (b2 % 96) * 32; r0 = (b2 / 96) * 32;
    } else {                               // transpose wout [1024][1024]
        int b2 = bid - 7424;
        in = wout; out = woutT; R = 1024; C = 1024;
        c0 = (b2 % 32) * 32; r0 = (b2 / 32) * 32;
    }
    int tx = tid & 31, ty = tid >> 5;      // 32 x 8
    for (int i = 0; i < 4; ++i)
        t[ty + i * 8][tx] = in[(size_t)(r0 + ty + i * 8) * C + c0 + tx];
    __syncthreads();
    for (int i = 0; i < 4; ++i)
        out[(size_t)(c0 + ty + i * 8) * R + r0 + tx] = f2bf(t[tx][ty + i * 8]);
}

// ---------------- out-proj GEMM (R25-proven): BK=64/barrier, XOR-swizzled LDS ----------------
__global__ __launch_bounds__(256) void gemm_out_kernel(const unsigned short* __restrict__ A,
                                                       const unsigned short* __restrict__ Bt,
                                                       float* __restrict__ Cout) {
    const int K = 1024, N = 1024;
    __shared__ __align__(16) unsigned short As[2][128 * 64];   // 16KB x2
    __shared__ __align__(16) unsigned short Bs[2][64 * 64];    // 8KB x2
    int tid = threadIdx.x;
    int lane = tid & 63;
    int w = tid >> 6;
    int wm = w >> 1, wn = w & 1;
    int m0 = blockIdx.y * 128, n0 = blockIdx.x * 64;
    int rq = lane >> 4, cl = lane & 15;

    f32x4 acc[4][2] = {};

    auto stage = [&](int k0, int buf) {
        #pragma unroll
        for (int i = 0; i < 4; ++i) {
            int c = i * 256 + tid;
            int r = c >> 3, c8 = c & 7;
            gload_lds16(A + (size_t)(m0 + r) * K + k0 + ((c8 ^ (r & 7)) * 8),
                        (char*)As[buf] + (size_t)(i * 256 + w * 64) * 16);
        }
        #pragma unroll
        for (int i = 0; i < 2; ++i) {
            int c = i * 256 + tid;
            int r = c >> 3, c8 = c & 7;
            gload_lds16(Bt + (size_t)(n0 + r) * K + k0 + ((c8 ^ (r & 7)) * 8),
                        (char*)Bs[buf] + (size_t)(i * 256 + w * 64) * 16);
        }
    };

    stage(0, 0);
    __syncthreads();
    int cur = 0;

    for (int rd = 0; rd < 16; ++rd) {
        short8 af[2][4], bfr[2][2];
        #pragma unroll
        for (int s = 0; s < 2; ++s) {
            #pragma unroll
            for (int mf = 0; mf < 4; ++mf) {
                int row = wm * 64 + mf * 16 + cl;
                af[s][mf] = __builtin_bit_cast(short8, *reinterpret_cast<const uint4*>(
                    (char*)As[cur] + row * 128 + (((s * 4 + rq) ^ (row & 7)) * 16)));
            }
            #pragma unroll
            for (int nf = 0; nf < 2; ++nf) {
                int row = wn * 32 + nf * 16 + cl;
                bfr[s][nf] = __builtin_bit_cast(short8, *reinterpret_cast<const uint4*>(
                    (char*)Bs[cur] + row * 128 + (((s * 4 + rq) ^ (row & 7)) * 16)));
            }
        }
        if (rd + 1 < 16) stage((rd + 1) * 64, cur ^ 1);
        __builtin_amdgcn_s_setprio(1);
        #pragma unroll
        for (int s = 0; s < 2; ++s)
            #pragma unroll
            for (int mf = 0; mf < 4; ++mf)
                #pragma unroll
                for (int nf = 0; nf < 2; ++nf)
                    acc[mf][nf] = __builtin_amdgcn_mfma_f32_16x16x32_bf16(af[s][mf], bfr[s][nf], acc[mf][nf], 0, 0, 0);
        __builtin_amdgcn_s_setprio(0);
        __syncthreads();
        cur ^= 1;
    }
    #pragma unroll
    for (int mf = 0; mf < 4; ++mf)
        #pragma unroll
        for (int nf = 0; nf < 2; ++nf)
            #pragma unroll
            for (int r = 0; r < 4; ++r) {
                size_t row = m0 + wm * 64 + mf * 16 + rq * 4 + r;
                size_t col = n0 + wn * 32 + nf * 16 + cl;
                Cout[row * N + col] = acc[mf][nf][r];
            }
}

// ---------------- fused qkv GEMM v26: BK=64 2-step rounds + XOR swizzle + RoPE/split/V^T ----------------
__global__ __launch_bounds__(256) void gemm_qkv_rope_kernel(const unsigned short* __restrict__ A,
                                                            const unsigned short* __restrict__ Bt,
                                                            const float* __restrict__ cosT,
                                                            const float* __restrict__ sinT,
                                                            unsigned short* __restrict__ Qb,
                                                            unsigned short* __restrict__ Kb,
                                                            unsigned short* __restrict__ VT) {
    const int K = 1024;
    __shared__ __align__(16) unsigned short As[2][128 * 64];   // 16KB x2
    __shared__ __align__(16) unsigned short Bs[2][128 * 64];   // 16KB x2
    int tid = threadIdx.x;
    int lane = tid & 63;
    int w = tid >> 6;
    int wm = w >> 1, wn = w & 1;
    int m0 = blockIdx.y * 128, n0 = blockIdx.x * 128;
    int rq = lane >> 4, cl = lane & 15;

    f32x4 acc[4][4] = {};

    // stage BK=64: A and B each 1024 chunks of 16B (4/thread); source chunk XOR row-swizzled
    auto stage = [&](int k0, int buf) {
        #pragma unroll
        for (int i = 0; i < 4; ++i) {
            int c = i * 256 + tid;
            int r = c >> 3, c8 = c & 7;
            gload_lds16(A + (size_t)(m0 + r) * K + k0 + ((c8 ^ (r & 7)) * 8),
                        (char*)As[buf] + (size_t)(i * 256 + w * 64) * 16);
            gload_lds16(Bt + (size_t)(n0 + r) * K + k0 + ((c8 ^ (r & 7)) * 8),
                        (char*)Bs[buf] + (size_t)(i * 256 + w * 64) * 16);
        }
    };

    stage(0, 0);
    __syncthreads();
    int cur = 0;

    for (int rd = 0; rd < 16; ++rd) {
        short8 af[2][4], bfr[2][4];
        #pragma unroll
        for (int s = 0; s < 2; ++s) {
            #pragma unroll
            for (int mf = 0; mf < 4; ++mf) {
                int row = wm * 64 + mf * 16 + cl;
                af[s][mf] = __builtin_bit_cast(short8, *reinterpret_cast<const uint4*>(
                    (char*)As[cur] + row * 128 + (((s * 4 + rq) ^ (row & 7)) * 16)));
            }
            #pragma unroll
            for (int nf = 0; nf < 4; ++nf) {
                int row = wn * 64 + nf * 16 + cl;
                bfr[s][nf] = __builtin_bit_cast(short8, *reinterpret_cast<const uint4*>(
                    (char*)Bs[cur] + row * 128 + (((s * 4 + rq) ^ (row & 7)) * 16)));
            }
        }
        if (rd + 1 < 16) stage((rd + 1) * 64, cur ^ 1);
        __builtin_amdgcn_s_setprio(1);
        #pragma unroll
        for (int s = 0; s < 2; ++s)
            #pragma unroll
            for (int mf = 0; mf < 4; ++mf)
                #pragma unroll
                for (int nf = 0; nf < 4; ++nf)
                    acc[mf][nf] = __builtin_amdgcn_mfma_f32_16x16x32_bf16(af[s][mf], bfr[s][nf], acc[mf][nf], 0, 0, 0);
        __builtin_amdgcn_s_setprio(0);
        __syncthreads();
        cur ^= 1;
    }

    const float QSCALE = 0.125f * 1.44269504088896f;
    int colbase = n0 + wn * 64;
    int sect = colbase >> 10;          // 0=Q, 1=K, 2=V
    int h = (colbase >> 6) & 15;
    #pragma unroll
    for (int mf = 0; mf < 4; ++mf) {
        int row0 = m0 + wm * 64 + mf * 16 + rq * 4;
        int b = row0 >> 11;
        int s0r = row0 & 2047;
        size_t ho = (size_t)(b * 16 + h);
        if (sect == 2) {
            #pragma unroll
            for (int nf = 0; nf < 4; ++nf) {
                int d = nf * 16 + cl;
                ushort4 o;
                o.x = f2bf(acc[mf][nf][0]);
                o.y = f2bf(acc[mf][nf][1]);
                o.z = f2bf(acc[mf][nf][2]);
                o.w = f2bf(acc[mf][nf][3]);
                *reinterpret_cast<ushort4*>(VT + (ho * 64 + d) * 2048 + s0r) = o;
            }
        } else {
            unsigned short* dst = (sect == 0) ? Qb : Kb;
            float scale = (sect == 0) ? QSCALE : 1.0f;
            #pragma unroll
            for (int nf = 0; nf < 4; ++nf) {
                int d = nf * 16 + cl;
                int f = ((nf & 1) << 4) + cl;
                #pragma unroll
                for (int r = 0; r < 4; ++r) {
                    int s = s0r + r;
                    float cs = cosT[s * 32 + f], sn = sinT[s * 32 + f];
                    float val = acc[mf][nf][r], pair = acc[mf][nf ^ 2][r];
                    float out = (nf < 2) ? val * cs - pair * sn : val * cs + pair * sn;
                    dst[(ho * 2048 + s) * 64 + d] = f2bf(out * scale);
                }
            }
        }
    }
}

// ---------------- flash attention v24 (best: 49.5us): 2-tile rounds, shared staging, triangle pairs ----------------
__global__ __launch_bounds__(256) void flash_attn_kernel(const unsigned short* __restrict__ Qb,
                                                         const unsigned short* __restrict__ Kb,
                                                         const unsigned short* __restrict__ VT,
                                                         unsigned short* __restrict__ Oattn) {
    const int S = 2048;
    __shared__ __align__(16) char smem[2 * 32768 + 512];   // 2 bufs x (K[2] 16K | V[2] 16K)
    int tid = threadIdx.x, lane = tid & 63, w = tid >> 6;
    int qsub = w & 1, kvh = w >> 1;
    int gid = blockIdx.x;
    int hh = gid & 31;                   // head -> fixed XCD (hh%8)
    int cp = gid >> 5;                   // 0..15
    size_t headOff = (size_t)hh * S * 64;
    const unsigned short* Kg = Kb + headOff;
    const unsigned short* Vg = VT + headOff;
    const uint4* Qg4 = reinterpret_cast<const uint4*>(Qb + headOff);
    int l31 = lane & 31, hi = lane >> 5;

    int sr[2], sj[2];
    #pragma unroll
    for (int i = 0; i < 2; ++i) {
        int cch = i * 256 + tid;
        sr[i] = cch >> 3;
        sj[i] = ((cch & 7) ^ (sr[i] & 7)) * 8;
    }
    float* mo = reinterpret_cast<float*>(smem);
    float* ml = reinterpret_cast<float*>(smem + 16384);

    #pragma unroll
    for (int ph = 0; ph < 2; ++ph) {
        int c = ph ? (31 - cp) : cp;
        int q0 = c * 64;
        int qw = q0 + qsub * 32;
        int qrow = qw + l31;

        short8 qf[4];
        #pragma unroll
        for (int cc = 0; cc < 4; ++cc)
            qf[cc] = ld_frag(Qg4, (size_t)qrow * 8 + cc * 2 + hi);

        f32x16 oacc0 = {}, oacc1 = {};
        float l = 0.f;
        int nk = c + 1;
        int nr = (nk + 1) >> 1;          // 2-tile rounds

        auto stage2 = [&](int rd, int b) {
            char* base = smem + b * 32768;
            #pragma unroll
            for (int sub = 0; sub < 2; ++sub) {
                int kt = 2 * rd + sub;
                if (kt < nk) {
                    int kn = kt * 64;
                    #pragma unroll
                    for (int i = 0; i < 2; ++i) {
                        gload_lds16(Kg + (size_t)(kn + sr[i]) * 64 + sj[i],
                                    base + sub * 8192 + (i * 256 + w * 64) * 16);
                        gload_lds16(Vg + (size_t)sr[i] * S + kn + sj[i],
                                    base + 16384 + sub * 8192 + (i * 256 + w * 64) * 16);
                    }
                }
            }
        };

        stage2(0, 0);
        __syncthreads();
        int cur = 0;

        for (int rd = 0; rd < nr; ++rd) {
            bool staged = false;
            #pragma unroll
            for (int sub = 0; sub < 2; ++sub) {
                int kt = 2 * rd + sub;
                int kvbase = kt * 64 + kvh * 32;
                bool active = (kt < nk) && (kvbase <= qw + 31);
                short8 ka[4], va[4];
                if (active) {
                    const char* Kt = smem + cur * 32768 + sub * 8192;
                    const char* Vt = smem + cur * 32768 + 16384 + sub * 8192;
                    int r = kvh * 32 + l31;
                    #pragma unroll
                    for (int cc = 0; cc < 4; ++cc)
                        ka[cc] = __builtin_bit_cast(short8, *reinterpret_cast<const uint4*>(
                            Kt + r * 128 + (((2 * cc + hi) ^ (r & 7)) * 16)));
                    #pragma unroll
                    for (int t = 0; t < 2; ++t) {
                        va[t] = __builtin_bit_cast(short8, *reinterpret_cast<const uint4*>(
                            Vt + l31 * 128 + (((kvh * 4 + 2 * t + hi) ^ (l31 & 7)) * 16)));
                        va[2 + t] = __builtin_bit_cast(short8, *reinterpret_cast<const uint4*>(
                            Vt + (32 + l31) * 128 + (((kvh * 4 + 2 * t + hi) ^ ((32 + l31) & 7)) * 16)));
                    }
                }
                if (!staged) {
                    if (rd + 1 < nr) stage2(rd + 1, cur ^ 1);
                    staged = true;
                }
                if (active) {
                    f32x16 s = {};
                    __builtin_amdgcn_s_setprio(1);
                    #pragma unroll
                    for (int cc = 0; cc < 4; ++cc)
                        s = __builtin_amdgcn_mfma_f32_32x32x16_bf16(ka[cc], qf[cc], s, 0, 0, 0);
                    __builtin_amdgcn_s_setprio(0);

                    if (kvbase + 31 > qw) {
                        #pragma unroll
                        for (int r = 0; r < 16; ++r) {
                            int kva = kvbase + (r & 3) + 8 * (r >> 2) + 4 * hi;
                            s[r] = (kva <= qrow) ? s[r] : -1e30f;
                        }
                    }
                    #pragma unroll
                    for (int r = 0; r < 16; ++r) s[r] = exp2f(s[r]);
                    float rp0 = ((s[0] + s[4]) + (s[8] + s[12])) + ((s[1] + s[5]) + (s[9] + s[13]));
                    float rp1 = ((s[2] + s[6]) + (s[10] + s[14])) + ((s[3] + s[7]) + (s[11] + s[15]));
                    float rs = rp0 + rp1;
                    rs += __shfl_xor(rs, 32);
                    l += rs;

                    unsigned wd[8];
                    #pragma unroll
                    for (int i = 0; i < 8; ++i) wd[i] = cvt_pk_bf16(s[2 * i], s[2 * i + 1]);
                    unsigned e0 = (unsigned)__shfl_xor((int)(hi ? wd[0] : wd[2]), 32);
                    unsigned e1 = (unsigned)__shfl_xor((int)(hi ? wd[1] : wd[3]), 32);
                    unsigned e2 = (unsigned)__shfl_xor((int)(hi ? wd[4] : wd[6]), 32);
                    unsigned e3 = (unsigned)__shfl_xor((int)(hi ? wd[5] : wd[7]), 32);
                    uint4 p0 = hi ? uint4{e0, e1, wd[2], wd[3]} : uint4{wd[0], wd[1], e0, e1};
                    uint4 p1 = hi ? uint4{e2, e3, wd[6], wd[7]} : uint4{wd[4], wd[5], e2, e3};
                    short8 pb0 = __builtin_bit_cast(short8, p0);
                    short8 pb1 = __builtin_bit_cast(short8, p1);

                    __builtin_amdgcn_s_setprio(1);
                    oacc0 = __builtin_amdgcn_mfma_f32_32x32x16_bf16(va[0], pb0, oacc0, 0, 0, 0);
                    oacc0 = __builtin_amdgcn_mfma_f32_32x32x16_bf16(va[1], pb1, oacc0, 0, 0, 0);
                    oacc1 = __builtin_amdgcn_mfma_f32_32x32x16_bf16(va[2], pb0, oacc1, 0, 0, 0);
                    oacc1 = __builtin_amdgcn_mfma_f32_32x32x16_bf16(va[3], pb1, oacc1, 0, 0, 0);
                    __builtin_amdgcn_s_setprio(0);
                }
            }
            __syncthreads();
            cur ^= 1;
        }

        if (kvh) {
            #pragma unroll
            for (int r = 0; r < 16; ++r) {
                mo[(r * 2 + qsub) * 64 + lane]        = oacc0[r];
                mo[((16 + r) * 2 + qsub) * 64 + lane] = oacc1[r];
            }
            ml[qsub * 64 + lane] = l;
        }
        __syncthreads();
        if (!kvh) {
            l += ml[qsub * 64 + lane];
            float invl = 1.f / l;
            size_t orow = ((size_t)((hh >> 4) * 2048 + qrow)) * 1024 + (hh & 15) * 64;
            #pragma unroll
            for (int du = 0; du < 2; ++du) {
                const f32x16& oa = du ? oacc1 : oacc0;
                #pragma unroll
                for (int gq = 0; gq < 4; ++gq) {
                    ushort4 o;
                    #pragma unroll
                    for (int e = 0; e < 4; ++e) {
                        int r = 4 * gq + e;
                        float v = (oa[r] + mo[((du * 16 + r) * 2 + qsub) * 64 + lane]) * invl;
                        ((unsigned short*)&o)[e] = f2bf(v);
                    }
                    int d = du * 32 + 4 * hi + 8 * gq;
                    *reinterpret_cast<ushort4*>(Oattn + orow + d) = o;
                }
            }
        }
        __syncthreads();   // smem readers done before next phase restages
    }
}

extern "C" void kernel_launch(void* const* d_in, const int* in_sizes, int n_in,
                              void* d_out, int out_size, void* d_ws, size_t ws_size,
                              hipStream_t stream) {
    const float* x    = (const float*)d_in[0];   // [2,2048,1024]
    const float* wqkv = (const float*)d_in[1];   // [1024,3072]
    const float* wout = (const float*)d_in[2];   // [1024,1024]

    char* ws = (char*)d_ws;
    unsigned short* xb    = (unsigned short*)(ws);                       // 8 MB
    unsigned short* wqkvT = (unsigned short*)(ws + (8ull  << 20));       // 6 MB
    unsigned short* woutT = (unsigned short*)(ws + (14ull << 20));       // 2 MB
    unsigned short* Qb    = (unsigned short*)(ws + (40ull << 20));       // 8 MB
    unsigned short* Kb    = (unsigned short*)(ws + (48ull << 20));       // 8 MB
    unsigned short* VT    = (unsigned short*)(ws + (56ull << 20));       // 8 MB
    unsigned short* Oat   = (unsigned short*)(ws + (64ull << 20));       // 8 MB
    float* cosT           = (float*)(ws + (72ull << 20));                // 256 KB
    float* sinT           = (float*)(ws + (72ull << 20) + (256u << 10)); // 256 KB

    prep_kernel<<<8448, 256, 0, stream>>>(x, xb, wqkv, wqkvT, wout, woutT, cosT, sinT);
    gemm_qkv_rope_kernel<<<dim3(24, 32), 256, 0, stream>>>(xb, wqkvT, cosT, sinT, Qb, Kb, VT);
    flash_attn_kernel<<<512, 256, 0, stream>>>(Qb, Kb, VT, Oat);
    gemm_out_kernel<<<dim3(16, 32), 256, 0, stream>>>(Oat, woutT, (float*)d_out);
}

// Round 27
// 106.571 us; speedup vs baseline: 1.0149x; 1.0149x over previous
//
#include <hip/hip_runtime.h>

typedef __attribute__((ext_vector_type(8))) short short8;
typedef __attribute__((ext_vector_type(4))) float f32x4;
typedef __attribute__((ext_vector_type(16))) float f32x16;

__device__ __forceinline__ unsigned short f2bf(float f) {
    unsigned u = __builtin_bit_cast(unsigned, f);
    u += 0x7FFFu + ((u >> 16) & 1u);
    return (unsigned short)(u >> 16);
}
__device__ __forceinline__ short8 ld_frag(const uint4* p, size_t idx16) {
    return __builtin_bit_cast(short8, p[idx16]);
}
__device__ __forceinline__ unsigned cvt_pk_bf16(float lo, float hi) {
    unsigned r;
    asm("v_cvt_pk_bf16_f32 %0, %1, %2" : "=v"(r) : "v"(lo), "v"(hi));
    return r;
}
// async global->LDS, 16B per lane; lds base must be wave-uniform (HW adds lane*16)
__device__ __forceinline__ void gload_lds16(const void* g, void* l) {
    __builtin_amdgcn_global_load_lds((const __attribute__((address_space(1))) void*)g,
                                     (__attribute__((address_space(3))) void*)l, 16, 0, 0);
}

// ---------------- prep: rope table + cast x + both weight transposes, one launch ----------------
__global__ __launch_bounds__(256) void prep_kernel(const float* __restrict__ x, unsigned short* __restrict__ xb,
                                                   const float* __restrict__ wqkv, unsigned short* __restrict__ wqkvT,
                                                   const float* __restrict__ wout, unsigned short* __restrict__ woutT,
                                                   float* __restrict__ cosT, float* __restrict__ sinT) {
    __shared__ float t[32][33];
    int bid = blockIdx.x, tid = threadIdx.x;
    if (bid < 256) {                       // rope table: [2048][32]
        int idx = bid * 256 + tid;
        int s = idx >> 5, i = idx & 31;
        // inv_freq = 10000^(-i/32) = 2^(-i*log2(10000)/32); log2(10000)=13.28771238
        float inv = exp2f(-(float)i * (13.28771238f / 32.f));
        float ang = (float)s * inv;
        cosT[idx] = cosf(ang);
        sinT[idx] = sinf(ang);
        return;
    }
    if (bid < 4352) {                      // cast x -> bf16, 4 elems/thread
        int i = (bid - 256) * 256 + tid;
        float4 v = reinterpret_cast<const float4*>(x)[i];
        ushort4 o;
        o.x = f2bf(v.x); o.y = f2bf(v.y); o.z = f2bf(v.z); o.w = f2bf(v.w);
        reinterpret_cast<ushort4*>(xb)[i] = o;
        return;
    }
    const float* in; unsigned short* out; int R, C, c0, r0;
    if (bid < 7424) {                      // transpose wqkv [1024][3072] -> [3072][1024]
        int b2 = bid - 4352;
        in = wqkv; out = wqkvT; R = 1024; C = 3072;
        c0 = (b2 % 96) * 32; r0 = (b2 / 96) * 32;
    } else {                               // transpose wout [1024][1024]
        int b2 = bid - 7424;
        in = wout; out = woutT; R = 1024; C = 1024;
        c0 = (b2 % 32) * 32; r0 = (b2 / 32) * 32;
    }
    int tx = tid & 31, ty = tid >> 5;      // 32 x 8
    for (int i = 0; i < 4; ++i)
        t[ty + i * 8][tx] = in[(size_t)(r0 + ty + i * 8) * C + c0 + tx];
    __syncthreads();
    for (int i = 0; i < 4; ++i)
        out[(size_t)(c0 + ty + i * 8) * R + r0 + tx] = f2bf(t[tx][ty + i * 8]);
}

// ---------------- out-proj GEMM (R25-proven): BK=64/barrier, XOR-swizzled LDS ----------------
__global__ __launch_bounds__(256) void gemm_out_kernel(const unsigned short* __restrict__ A,
                                                       const unsigned short* __restrict__ Bt,
                                                       float* __restrict__ Cout) {
    const int K = 1024, N = 1024;
    __shared__ __align__(16) unsigned short As[2][128 * 64];   // 16KB x2
    __shared__ __align__(16) unsigned short Bs[2][64 * 64];    // 8KB x2
    int tid = threadIdx.x;
    int lane = tid & 63;
    int w = tid >> 6;
    int wm = w >> 1, wn = w & 1;
    int m0 = blockIdx.y * 128, n0 = blockIdx.x * 64;
    int rq = lane >> 4, cl = lane & 15;

    f32x4 acc[4][2] = {};

    auto stage = [&](int k0, int buf) {
        #pragma unroll
        for (int i = 0; i < 4; ++i) {
            int c = i * 256 + tid;
            int r = c >> 3, c8 = c & 7;
            gload_lds16(A + (size_t)(m0 + r) * K + k0 + ((c8 ^ (r & 7)) * 8),
                        (char*)As[buf] + (size_t)(i * 256 + w * 64) * 16);
        }
        #pragma unroll
        for (int i = 0; i < 2; ++i) {
            int c = i * 256 + tid;
            int r = c >> 3, c8 = c & 7;
            gload_lds16(Bt + (size_t)(n0 + r) * K + k0 + ((c8 ^ (r & 7)) * 8),
                        (char*)Bs[buf] + (size_t)(i * 256 + w * 64) * 16);
        }
    };

    stage(0, 0);
    __syncthreads();
    int cur = 0;

    for (int rd = 0; rd < 16; ++rd) {
        short8 af[2][4], bfr[2][2];
        #pragma unroll
        for (int s = 0; s < 2; ++s) {
            #pragma unroll
            for (int mf = 0; mf < 4; ++mf) {
                int row = wm * 64 + mf * 16 + cl;
                af[s][mf] = __builtin_bit_cast(short8, *reinterpret_cast<const uint4*>(
                    (char*)As[cur] + row * 128 + (((s * 4 + rq) ^ (row & 7)) * 16)));
            }
            #pragma unroll
            for (int nf = 0; nf < 2; ++nf) {
                int row = wn * 32 + nf * 16 + cl;
                bfr[s][nf] = __builtin_bit_cast(short8, *reinterpret_cast<const uint4*>(
                    (char*)Bs[cur] + row * 128 + (((s * 4 + rq) ^ (row & 7)) * 16)));
            }
        }
        if (rd + 1 < 16) stage((rd + 1) * 64, cur ^ 1);
        __builtin_amdgcn_s_setprio(1);
        #pragma unroll
        for (int s = 0; s < 2; ++s)
            #pragma unroll
            for (int mf = 0; mf < 4; ++mf)
                #pragma unroll
                for (int nf = 0; nf < 2; ++nf)
                    acc[mf][nf] = __builtin_amdgcn_mfma_f32_16x16x32_bf16(af[s][mf], bfr[s][nf], acc[mf][nf], 0, 0, 0);
        __builtin_amdgcn_s_setprio(0);
        __syncthreads();
        cur ^= 1;
    }
    #pragma unroll
    for (int mf = 0; mf < 4; ++mf)
        #pragma unroll
        for (int nf = 0; nf < 2; ++nf)
            #pragma unroll
            for (int r = 0; r < 4; ++r) {
                size_t row = m0 + wm * 64 + mf * 16 + rq * 4 + r;
                size_t col = n0 + wn * 32 + nf * 16 + cl;
                Cout[row * N + col] = acc[mf][nf][r];
            }
}

// ---------------- fused qkv GEMM (R25-proven): BK=32 dbuf + XOR swizzle + RoPE/split/V^T ----------------
__global__ __launch_bounds__(256) void gemm_qkv_rope_kernel(const unsigned short* __restrict__ A,
                                                            const unsigned short* __restrict__ Bt,
                                                            const float* __restrict__ cosT,
                                                            const float* __restrict__ sinT,
                                                            unsigned short* __restrict__ Qb,
                                                            unsigned short* __restrict__ Kb,
                                                            unsigned short* __restrict__ VT) {
    const int K = 1024;
    __shared__ __align__(16) unsigned short As[2][128 * 32];
    __shared__ __align__(16) unsigned short Bs[2][128 * 32];
    int tid = threadIdx.x;
    int lane = tid & 63;
    int w = tid >> 6;
    int wm = w >> 1, wn = w & 1;
    int m0 = blockIdx.y * 128, n0 = blockIdx.x * 128;
    int rq = lane >> 4, cl = lane & 15;

    f32x4 acc[4][4] = {};

    // stage: 512 chunks each (2/thread); source chunk XOR row-swizzled (4 chunks/row, r&3)
    auto stage = [&](int k0, int buf) {
        #pragma unroll
        for (int i = 0; i < 2; ++i) {
            int c = i * 256 + tid;
            int r = c >> 2, c4 = c & 3;
            gload_lds16(A + (size_t)(m0 + r) * K + k0 + ((c4 ^ (r & 3)) * 8),
                        (char*)As[buf] + (size_t)(i * 256 + w * 64) * 16);
            gload_lds16(Bt + (size_t)(n0 + r) * K + k0 + ((c4 ^ (r & 3)) * 8),
                        (char*)Bs[buf] + (size_t)(i * 256 + w * 64) * 16);
        }
    };

    stage(0, 0);
    __syncthreads();
    int cur = 0;

    for (int k0 = 0; k0 < K; k0 += 32) {
        short8 af[4], bfr[4];
        #pragma unroll
        for (int mf = 0; mf < 4; ++mf) {
            int row = wm * 64 + mf * 16 + cl;
            af[mf] = __builtin_bit_cast(short8, *reinterpret_cast<const uint4*>(
                (char*)As[cur] + row * 64 + ((rq ^ (row & 3)) * 16)));
        }
        #pragma unroll
        for (int nf = 0; nf < 4; ++nf) {
            int row = wn * 64 + nf * 16 + cl;
            bfr[nf] = __builtin_bit_cast(short8, *reinterpret_cast<const uint4*>(
                (char*)Bs[cur] + row * 64 + ((rq ^ (row & 3)) * 16)));
        }
        if (k0 + 32 < K) stage(k0 + 32, cur ^ 1);
        __builtin_amdgcn_s_setprio(1);
        #pragma unroll
        for (int mf = 0; mf < 4; ++mf)
            #pragma unroll
            for (int nf = 0; nf < 4; ++nf)
                acc[mf][nf] = __builtin_amdgcn_mfma_f32_16x16x32_bf16(af[mf], bfr[nf], acc[mf][nf], 0, 0, 0);
        __builtin_amdgcn_s_setprio(0);
        __syncthreads();
        cur ^= 1;
    }

    const float QSCALE = 0.125f * 1.44269504088896f;
    int colbase = n0 + wn * 64;
    int sect = colbase >> 10;          // 0=Q, 1=K, 2=V
    int h = (colbase >> 6) & 15;
    #pragma unroll
    for (int mf = 0; mf < 4; ++mf) {
        int row0 = m0 + wm * 64 + mf * 16 + rq * 4;
        int b = row0 >> 11;
        int s0r = row0 & 2047;
        size_t ho = (size_t)(b * 16 + h);
        if (sect == 2) {
            #pragma unroll
            for (int nf = 0; nf < 4; ++nf) {
                int d = nf * 16 + cl;
                ushort4 o;
                o.x = f2bf(acc[mf][nf][0]);
                o.y = f2bf(acc[mf][nf][1]);
                o.z = f2bf(acc[mf][nf][2]);
                o.w = f2bf(acc[mf][nf][3]);
                *reinterpret_cast<ushort4*>(VT + (ho * 64 + d) * 2048 + s0r) = o;
            }
        } else {
            unsigned short* dst = (sect == 0) ? Qb : Kb;
            float scale = (sect == 0) ? QSCALE : 1.0f;
            #pragma unroll
            for (int nf = 0; nf < 4; ++nf) {
                int d = nf * 16 + cl;
                int f = ((nf & 1) << 4) + cl;
                #pragma unroll
                for (int r = 0; r < 4; ++r) {
                    int s = s0r + r;
                    float cs = cosT[s * 32 + f], sn = sinT[s * 32 + f];
                    float val = acc[mf][nf][r], pair = acc[mf][nf ^ 2][r];
                    float out = (nf < 2) ? val * cs - pair * sn : val * cs + pair * sn;
                    dst[(ho * 2048 + s) * 64 + d] = f2bf(out * scale);
                }
            }
        }
    }
}

// ---------------- flash attention v24 (best: 49.5us): 2-tile rounds, shared staging, triangle pairs ----------------
__global__ __launch_bounds__(256) void flash_attn_kernel(const unsigned short* __restrict__ Qb,
                                                         const unsigned short* __restrict__ Kb,
                                                         const unsigned short* __restrict__ VT,
                                                         unsigned short* __restrict__ Oattn) {
    const int S = 2048;
    __shared__ __align__(16) char smem[2 * 32768 + 512];   // 2 bufs x (K[2] 16K | V[2] 16K)
    int tid = threadIdx.x, lane = tid & 63, w = tid >> 6;
    int qsub = w & 1, kvh = w >> 1;
    int gid = blockIdx.x;
    int hh = gid & 31;                   // head -> fixed XCD (hh%8)
    int cp = gid >> 5;                   // 0..15
    size_t headOff = (size_t)hh * S * 64;
    const unsigned short* Kg = Kb + headOff;
    const unsigned short* Vg = VT + headOff;
    const uint4* Qg4 = reinterpret_cast<const uint4*>(Qb + headOff);
    int l31 = lane & 31, hi = lane >> 5;

    int sr[2], sj[2];
    #pragma unroll
    for (int i = 0; i < 2; ++i) {
        int cch = i * 256 + tid;
        sr[i] = cch >> 3;
        sj[i] = ((cch & 7) ^ (sr[i] & 7)) * 8;
    }
    float* mo = reinterpret_cast<float*>(smem);
    float* ml = reinterpret_cast<float*>(smem + 16384);

    #pragma unroll
    for (int ph = 0; ph < 2; ++ph) {
        int c = ph ? (31 - cp) : cp;
        int q0 = c * 64;
        int qw = q0 + qsub * 32;
        int qrow = qw + l31;

        short8 qf[4];
        #pragma unroll
        for (int cc = 0; cc < 4; ++cc)
            qf[cc] = ld_frag(Qg4, (size_t)qrow * 8 + cc * 2 + hi);

        f32x16 oacc0 = {}, oacc1 = {};
        float l = 0.f;
        int nk = c + 1;
        int nr = (nk + 1) >> 1;          // 2-tile rounds

        auto stage2 = [&](int rd, int b) {
            char* base = smem + b * 32768;
            #pragma unroll
            for (int sub = 0; sub < 2; ++sub) {
                int kt = 2 * rd + sub;
                if (kt < nk) {
                    int kn = kt * 64;
                    #pragma unroll
                    for (int i = 0; i < 2; ++i) {
                        gload_lds16(Kg + (size_t)(kn + sr[i]) * 64 + sj[i],
                                    base + sub * 8192 + (i * 256 + w * 64) * 16);
                        gload_lds16(Vg + (size_t)sr[i] * S + kn + sj[i],
                                    base + 16384 + sub * 8192 + (i * 256 + w * 64) * 16);
                    }
                }
            }
        };

        stage2(0, 0);
        __syncthreads();
        int cur = 0;

        for (int rd = 0; rd < nr; ++rd) {
            bool staged = false;
            #pragma unroll
            for (int sub = 0; sub < 2; ++sub) {
                int kt = 2 * rd + sub;
                int kvbase = kt * 64 + kvh * 32;
                bool active = (kt < nk) && (kvbase <= qw + 31);
                short8 ka[4], va[4];
                if (active) {
                    const char* Kt = smem + cur * 32768 + sub * 8192;
                    const char* Vt = smem + cur * 32768 + 16384 + sub * 8192;
                    int r = kvh * 32 + l31;
                    #pragma unroll
                    for (int cc = 0; cc < 4; ++cc)
                        ka[cc] = __builtin_bit_cast(short8, *reinterpret_cast<const uint4*>(
                            Kt + r * 128 + (((2 * cc + hi) ^ (r & 7)) * 16)));
                    #pragma unroll
                    for (int t = 0; t < 2; ++t) {
                        va[t] = __builtin_bit_cast(short8, *reinterpret_cast<const uint4*>(
                            Vt + l31 * 128 + (((kvh * 4 + 2 * t + hi) ^ (l31 & 7)) * 16)));
                        va[2 + t] = __builtin_bit_cast(short8, *reinterpret_cast<const uint4*>(
                            Vt + (32 + l31) * 128 + (((kvh * 4 + 2 * t + hi) ^ ((32 + l31) & 7)) * 16)));
                    }
                }
                if (!staged) {
                    if (rd + 1 < nr) stage2(rd + 1, cur ^ 1);
                    staged = true;
                }
                if (active) {
                    f32x16 s = {};
                    __builtin_amdgcn_s_setprio(1);
                    #pragma unroll
                    for (int cc = 0; cc < 4; ++cc)
                        s = __builtin_amdgcn_mfma_f32_32x32x16_bf16(ka[cc], qf[cc], s, 0, 0, 0);
                    __builtin_amdgcn_s_setprio(0);

                    if (kvbase + 31 > qw) {
                        #pragma unroll
                        for (int r = 0; r < 16; ++r) {
                            int kva = kvbase + (r & 3) + 8 * (r >> 2) + 4 * hi;
                            s[r] = (kva <= qrow) ? s[r] : -1e30f;
                        }
                    }
                    #pragma unroll
                    for (int r = 0; r < 16; ++r) s[r] = exp2f(s[r]);
                    float rp0 = ((s[0] + s[4]) + (s[8] + s[12])) + ((s[1] + s[5]) + (s[9] + s[13]));
                    float rp1 = ((s[2] + s[6]) + (s[10] + s[14])) + ((s[3] + s[7]) + (s[11] + s[15]));
                    float rs = rp0 + rp1;
                    rs += __shfl_xor(rs, 32);
                    l += rs;

                    unsigned wd[8];
                    #pragma unroll
                    for (int i = 0; i < 8; ++i) wd[i] = cvt_pk_bf16(s[2 * i], s[2 * i + 1]);
                    unsigned e0 = (unsigned)__shfl_xor((int)(hi ? wd[0] : wd[2]), 32);
                    unsigned e1 = (unsigned)__shfl_xor((int)(hi ? wd[1] : wd[3]), 32);
                    unsigned e2 = (unsigned)__shfl_xor((int)(hi ? wd[4] : wd[6]), 32);
                    unsigned e3 = (unsigned)__shfl_xor((int)(hi ? wd[5] : wd[7]), 32);
                    uint4 p0 = hi ? uint4{e0, e1, wd[2], wd[3]} : uint4{wd[0], wd[1], e0, e1};
                    uint4 p1 = hi ? uint4{e2, e3, wd[6], wd[7]} : uint4{wd[4], wd[5], e2, e3};
                    short8 pb0 = __builtin_bit_cast(short8, p0);
                    short8 pb1 = __builtin_bit_cast(short8, p1);

                    __builtin_amdgcn_s_setprio(1);
                    oacc0 = __builtin_amdgcn_mfma_f32_32x32x16_bf16(va[0], pb0, oacc0, 0, 0, 0);
                    oacc0 = __builtin_amdgcn_mfma_f32_32x32x16_bf16(va[1], pb1, oacc0, 0, 0, 0);
                    oacc1 = __builtin_amdgcn_mfma_f32_32x32x16_bf16(va[2], pb0, oacc1, 0, 0, 0);
                    oacc1 = __builtin_amdgcn_mfma_f32_32x32x16_bf16(va[3], pb1, oacc1, 0, 0, 0);
                    __builtin_amdgcn_s_setprio(0);
                }
            }
            __syncthreads();
            cur ^= 1;
        }

        if (kvh) {
            #pragma unroll
            for (int r = 0; r < 16; ++r) {
                mo[(r * 2 + qsub) * 64 + lane]        = oacc0[r];
                mo[((16 + r) * 2 + qsub) * 64 + lane] = oacc1[r];
            }
            ml[qsub * 64 + lane] = l;
        }
        __syncthreads();
        if (!kvh) {
            l += ml[qsub * 64 + lane];
            float invl = 1.f / l;
            size_t orow = ((size_t)((hh >> 4) * 2048 + qrow)) * 1024 + (hh & 15) * 64;
            #pragma unroll
            for (int du = 0; du < 2; ++du) {
                const f32x16& oa = du ? oacc1 : oacc0;
                #pragma unroll
                for (int gq = 0; gq < 4; ++gq) {
                    ushort4 o;
                    #pragma unroll
                    for (int e = 0; e < 4; ++e) {
                        int r = 4 * gq + e;
                        float v = (oa[r] + mo[((du * 16 + r) * 2 + qsub) * 64 + lane]) * invl;
                        ((unsigned short*)&o)[e] = f2bf(v);
                    }
                    int d = du * 32 + 4 * hi + 8 * gq;
                    *reinterpret_cast<ushort4*>(Oattn + orow + d) = o;
                }
            }
        }
        __syncthreads();   // smem readers done before next phase restages
    }
}

extern "C" void kernel_launch(void* const* d_in, const int* in_sizes, int n_in,
                              void* d_out, int out_size, void* d_ws, size_t ws_size,
                              hipStream_t stream) {
    const float* x    = (const float*)d_in[0];   // [2,2048,1024]
    const float* wqkv = (const float*)d_in[1];   // [1024,3072]
    const float* wout = (const float*)d_in[2];   // [1024,1024]

    char* ws = (char*)d_ws;
    unsigned short* xb    = (unsigned short*)(ws);                       // 8 MB
    unsigned short* wqkvT = (unsigned short*)(ws + (8ull  << 20));       // 6 MB
    unsigned short* woutT = (unsigned short*)(ws + (14ull << 20));       // 2 MB
    unsigned short* Qb    = (unsigned short*)(ws + (40ull << 20));       // 8 MB
    unsigned short* Kb    = (unsigned short*)(ws + (48ull << 20));       // 8 MB
    unsigned short* VT    = (unsigned short*)(ws + (56ull << 20));       // 8 MB
    unsigned short* Oat   = (unsigned short*)(ws + (64ull << 20));       // 8 MB
    float* cosT           = (float*)(ws + (72ull << 20));                // 256 KB
    float* sinT           = (float*)(ws + (72ull << 20) + (256u << 10)); // 256 KB

    prep_kernel<<<8448, 256, 0, stream>>>(x, xb, wqkv, wqkvT, wout, woutT, cosT, sinT);
    gemm_qkv_rope_kernel<<<dim3(24, 32), 256, 0, stream>>>(xb, wqkvT, cosT, sinT, Qb, Kb, VT);
    flash_attn_kernel<<<512, 256, 0, stream>>>(Qb, Kb, VT, Oat);
    gemm_out_kernel<<<dim3(16, 32), 256, 0, stream>>>(Oat, woutT, (float*)d_out);
}

// Round 28
// 106.089 us; speedup vs baseline: 1.0195x; 1.0045x over previous
//
#include <hip/hip_runtime.h>

typedef __attribute__((ext_vector_type(8))) short short8;
typedef __attribute__((ext_vector_type(4))) float f32x4;
typedef __attribute__((ext_vector_type(16))) float f32x16;

__device__ __forceinline__ unsigned short f2bf(float f) {
    unsigned u = __builtin_bit_cast(unsigned, f);
    u += 0x7FFFu + ((u >> 16) & 1u);
    return (unsigned short)(u >> 16);
}
__device__ __forceinline__ short8 ld_frag(const uint4* p, size_t idx16) {
    return __builtin_bit_cast(short8, p[idx16]);
}
__device__ __forceinline__ unsigned cvt_pk_bf16(float lo, float hi) {
    unsigned r;
    asm("v_cvt_pk_bf16_f32 %0, %1, %2" : "=v"(r) : "v"(lo), "v"(hi));
    return r;
}
// async global->LDS, 16B per lane; lds base must be wave-uniform (HW adds lane*16)
__device__ __forceinline__ void gload_lds16(const void* g, void* l) {
    __builtin_amdgcn_global_load_lds((const __attribute__((address_space(1))) void*)g,
                                     (__attribute__((address_space(3))) void*)l, 16, 0, 0);
}

// ---------------- prep v2: rope table + vectorized cast x + vectorized 64x64 transposes ----------------
// Grid: [0,256) rope | [256,2304) cast x (8 f/thread) | [2304,3072) wqkv T | [3072,3328) wout T
__global__ __launch_bounds__(256) void prep_kernel(const float* __restrict__ x, unsigned short* __restrict__ xb,
                                                   const float* __restrict__ wqkv, unsigned short* __restrict__ wqkvT,
                                                   const float* __restrict__ wout, unsigned short* __restrict__ woutT,
                                                   float* __restrict__ cosT, float* __restrict__ sinT) {
    __shared__ float t[64][65];
    int bid = blockIdx.x, tid = threadIdx.x;
    if (bid < 256) {                       // rope table: [2048][32]
        int idx = bid * 256 + tid;
        int s = idx >> 5, i = idx & 31;
        float inv = exp2f(-(float)i * (13.28771238f / 32.f));   // 10000^(-i/32)
        float ang = (float)s * inv;
        cosT[idx] = cosf(ang);
        sinT[idx] = sinf(ang);
        return;
    }
    if (bid < 2304) {                      // cast x -> bf16, 8 elems/thread, 16B stores
        int i = (bid - 256) * 256 + tid;
        const float4* x4 = reinterpret_cast<const float4*>(x);
        float4 a = x4[2 * i], b = x4[2 * i + 1];
        uint4 o;
        o.x = cvt_pk_bf16(a.x, a.y);
        o.y = cvt_pk_bf16(a.z, a.w);
        o.z = cvt_pk_bf16(b.x, b.y);
        o.w = cvt_pk_bf16(b.z, b.w);
        reinterpret_cast<uint4*>(xb)[i] = o;
        return;
    }
    const float* in; unsigned short* out; int R, C, c0, r0;
    if (bid < 3072) {                      // transpose wqkv [1024][3072] -> [3072][1024], 64x64 tiles
        int b2 = bid - 2304;               // 768 blocks = 48 col-tiles x 16 row-tiles
        in = wqkv; out = wqkvT; R = 1024; C = 3072;
        c0 = (b2 % 48) * 64; r0 = (b2 / 48) * 64;
    } else {                               // transpose wout [1024][1024], 256 blocks = 16 x 16
        int b2 = bid - 3072;
        in = wout; out = woutT; R = 1024; C = 1024;
        c0 = (b2 % 16) * 64; r0 = (b2 / 16) * 64;
    }
    {
        int tx = tid & 15, ty = tid >> 4;  // 16 float4-cols x 16 rows
        #pragma unroll
        for (int i = 0; i < 4; ++i) {
            int row = ty + 16 * i;
            float4 v = *reinterpret_cast<const float4*>(in + (size_t)(r0 + row) * C + c0 + tx * 4);
            t[row][tx * 4 + 0] = v.x;
            t[row][tx * 4 + 1] = v.y;
            t[row][tx * 4 + 2] = v.z;
            t[row][tx * 4 + 3] = v.w;
        }
        __syncthreads();
        int ocx = tid & 15, oty = tid >> 4;  // ocx: 4-row chunk (input rows = output cols), oty: output row
        #pragma unroll
        for (int i = 0; i < 4; ++i) {
            int oc = oty + 16 * i;           // input col = output row
            ushort4 o;
            o.x = f2bf(t[ocx * 4 + 0][oc]);
            o.y = f2bf(t[ocx * 4 + 1][oc]);
            o.z = f2bf(t[ocx * 4 + 2][oc]);
            o.w = f2bf(t[ocx * 4 + 3][oc]);
            *reinterpret_cast<ushort4*>(out + (size_t)(c0 + oc) * R + r0 + ocx * 4) = o;
        }
    }
}

// ---------------- out-proj GEMM (R25-proven): BK=64/barrier, XOR-swizzled LDS ----------------
__global__ __launch_bounds__(256) void gemm_out_kernel(const unsigned short* __restrict__ A,
                                                       const unsigned short* __restrict__ Bt,
                                                       float* __restrict__ Cout) {
    const int K = 1024, N = 1024;
    __shared__ __align__(16) unsigned short As[2][128 * 64];   // 16KB x2
    __shared__ __align__(16) unsigned short Bs[2][64 * 64];    // 8KB x2
    int tid = threadIdx.x;
    int lane = tid & 63;
    int w = tid >> 6;
    int wm = w >> 1, wn = w & 1;
    int m0 = blockIdx.y * 128, n0 = blockIdx.x * 64;
    int rq = lane >> 4, cl = lane & 15;

    f32x4 acc[4][2] = {};

    auto stage = [&](int k0, int buf) {
        #pragma unroll
        for (int i = 0; i < 4; ++i) {
            int c = i * 256 + tid;
            int r = c >> 3, c8 = c & 7;
            gload_lds16(A + (size_t)(m0 + r) * K + k0 + ((c8 ^ (r & 7)) * 8),
                        (char*)As[buf] + (size_t)(i * 256 + w * 64) * 16);
        }
        #pragma unroll
        for (int i = 0; i < 2; ++i) {
            int c = i * 256 + tid;
            int r = c >> 3, c8 = c & 7;
            gload_lds16(Bt + (size_t)(n0 + r) * K + k0 + ((c8 ^ (r & 7)) * 8),
                        (char*)Bs[buf] + (size_t)(i * 256 + w * 64) * 16);
        }
    };

    stage(0, 0);
    __syncthreads();
    int cur = 0;

    for (int rd = 0; rd < 16; ++rd) {
        short8 af[2][4], bfr[2][2];
        #pragma unroll
        for (int s = 0; s < 2; ++s) {
            #pragma unroll
            for (int mf = 0; mf < 4; ++mf) {
                int row = wm * 64 + mf * 16 + cl;
                af[s][mf] = __builtin_bit_cast(short8, *reinterpret_cast<const uint4*>(
                    (char*)As[cur] + row * 128 + (((s * 4 + rq) ^ (row & 7)) * 16)));
            }
            #pragma unroll
            for (int nf = 0; nf < 2; ++nf) {
                int row = wn * 32 + nf * 16 + cl;
                bfr[s][nf] = __builtin_bit_cast(short8, *reinterpret_cast<const uint4*>(
                    (char*)Bs[cur] + row * 128 + (((s * 4 + rq) ^ (row & 7)) * 16)));
            }
        }
        if (rd + 1 < 16) stage((rd + 1) * 64, cur ^ 1);
        __builtin_amdgcn_s_setprio(1);
        #pragma unroll
        for (int s = 0; s < 2; ++s)
            #pragma unroll
            for (int mf = 0; mf < 4; ++mf)
                #pragma unroll
                for (int nf = 0; nf < 2; ++nf)
                    acc[mf][nf] = __builtin_amdgcn_mfma_f32_16x16x32_bf16(af[s][mf], bfr[s][nf], acc[mf][nf], 0, 0, 0);
        __builtin_amdgcn_s_setprio(0);
        __syncthreads();
        cur ^= 1;
    }
    #pragma unroll
    for (int mf = 0; mf < 4; ++mf)
        #pragma unroll
        for (int nf = 0; nf < 2; ++nf)
            #pragma unroll
            for (int r = 0; r < 4; ++r) {
                size_t row = m0 + wm * 64 + mf * 16 + rq * 4 + r;
                size_t col = n0 + wn * 32 + nf * 16 + cl;
                Cout[row * N + col] = acc[mf][nf][r];
            }
}

// ---------------- fused qkv GEMM (R25-proven): BK=32 dbuf + XOR swizzle + RoPE/split/V^T ----------------
__global__ __launch_bounds__(256) void gemm_qkv_rope_kernel(const unsigned short* __restrict__ A,
                                                            const unsigned short* __restrict__ Bt,
                                                            const float* __restrict__ cosT,
                                                            const float* __restrict__ sinT,
                                                            unsigned short* __restrict__ Qb,
                                                            unsigned short* __restrict__ Kb,
                                                            unsigned short* __restrict__ VT) {
    const int K = 1024;
    __shared__ __align__(16) unsigned short As[2][128 * 32];
    __shared__ __align__(16) unsigned short Bs[2][128 * 32];
    int tid = threadIdx.x;
    int lane = tid & 63;
    int w = tid >> 6;
    int wm = w >> 1, wn = w & 1;
    int m0 = blockIdx.y * 128, n0 = blockIdx.x * 128;
    int rq = lane >> 4, cl = lane & 15;

    f32x4 acc[4][4] = {};

    auto stage = [&](int k0, int buf) {
        #pragma unroll
        for (int i = 0; i < 2; ++i) {
            int c = i * 256 + tid;
            int r = c >> 2, c4 = c & 3;
            gload_lds16(A + (size_t)(m0 + r) * K + k0 + ((c4 ^ (r & 3)) * 8),
                        (char*)As[buf] + (size_t)(i * 256 + w * 64) * 16);
            gload_lds16(Bt + (size_t)(n0 + r) * K + k0 + ((c4 ^ (r & 3)) * 8),
                        (char*)Bs[buf] + (size_t)(i * 256 + w * 64) * 16);
        }
    };

    stage(0, 0);
    __syncthreads();
    int cur = 0;

    for (int k0 = 0; k0 < K; k0 += 32) {
        short8 af[4], bfr[4];
        #pragma unroll
        for (int mf = 0; mf < 4; ++mf) {
            int row = wm * 64 + mf * 16 + cl;
            af[mf] = __builtin_bit_cast(short8, *reinterpret_cast<const uint4*>(
                (char*)As[cur] + row * 64 + ((rq ^ (row & 3)) * 16)));
        }
        #pragma unroll
        for (int nf = 0; nf < 4; ++nf) {
            int row = wn * 64 + nf * 16 + cl;
            bfr[nf] = __builtin_bit_cast(short8, *reinterpret_cast<const uint4*>(
                (char*)Bs[cur] + row * 64 + ((rq ^ (row & 3)) * 16)));
        }
        if (k0 + 32 < K) stage(k0 + 32, cur ^ 1);
        __builtin_amdgcn_s_setprio(1);
        #pragma unroll
        for (int mf = 0; mf < 4; ++mf)
            #pragma unroll
            for (int nf = 0; nf < 4; ++nf)
                acc[mf][nf] = __builtin_amdgcn_mfma_f32_16x16x32_bf16(af[mf], bfr[nf], acc[mf][nf], 0, 0, 0);
        __builtin_amdgcn_s_setprio(0);
        __syncthreads();
        cur ^= 1;
    }

    const float QSCALE = 0.125f * 1.44269504088896f;
    int colbase = n0 + wn * 64;
    int sect = colbase >> 10;          // 0=Q, 1=K, 2=V
    int h = (colbase >> 6) & 15;
    #pragma unroll
    for (int mf = 0; mf < 4; ++mf) {
        int row0 = m0 + wm * 64 + mf * 16 + rq * 4;
        int b = row0 >> 11;
        int s0r = row0 & 2047;
        size_t ho = (size_t)(b * 16 + h);
        if (sect == 2) {
            #pragma unroll
            for (int nf = 0; nf < 4; ++nf) {
                int d = nf * 16 + cl;
                ushort4 o;
                o.x = f2bf(acc[mf][nf][0]);
                o.y = f2bf(acc[mf][nf][1]);
                o.z = f2bf(acc[mf][nf][2]);
                o.w = f2bf(acc[mf][nf][3]);
                *reinterpret_cast<ushort4*>(VT + (ho * 64 + d) * 2048 + s0r) = o;
            }
        } else {
            unsigned short* dst = (sect == 0) ? Qb : Kb;
            float scale = (sect == 0) ? QSCALE : 1.0f;
            #pragma unroll
            for (int nf = 0; nf < 4; ++nf) {
                int d = nf * 16 + cl;
                int f = ((nf & 1) << 4) + cl;
                #pragma unroll
                for (int r = 0; r < 4; ++r) {
                    int s = s0r + r;
                    float cs = cosT[s * 32 + f], sn = sinT[s * 32 + f];
                    float val = acc[mf][nf][r], pair = acc[mf][nf ^ 2][r];
                    float out = (nf < 2) ? val * cs - pair * sn : val * cs + pair * sn;
                    dst[(ho * 2048 + s) * 64 + d] = f2bf(out * scale);
                }
            }
        }
    }
}

// ---------------- flash attention v24 (best: 49.5us): 2-tile rounds, shared staging, triangle pairs ----------------
__global__ __launch_bounds__(256) void flash_attn_kernel(const unsigned short* __restrict__ Qb,
                                                         const unsigned short* __restrict__ Kb,
                                                         const unsigned short* __restrict__ VT,
                                                         unsigned short* __restrict__ Oattn) {
    const int S = 2048;
    __shared__ __align__(16) char smem[2 * 32768 + 512];   // 2 bufs x (K[2] 16K | V[2] 16K)
    int tid = threadIdx.x, lane = tid & 63, w = tid >> 6;
    int qsub = w & 1, kvh = w >> 1;
    int gid = blockIdx.x;
    int hh = gid & 31;                   // head -> fixed XCD (hh%8)
    int cp = gid >> 5;                   // 0..15
    size_t headOff = (size_t)hh * S * 64;
    const unsigned short* Kg = Kb + headOff;
    const unsigned short* Vg = VT + headOff;
    const uint4* Qg4 = reinterpret_cast<const uint4*>(Qb + headOff);
    int l31 = lane & 31, hi = lane >> 5;

    int sr[2], sj[2];
    #pragma unroll
    for (int i = 0; i < 2; ++i) {
        int cch = i * 256 + tid;
        sr[i] = cch >> 3;
        sj[i] = ((cch & 7) ^ (sr[i] & 7)) * 8;
    }
    float* mo = reinterpret_cast<float*>(smem);
    float* ml = reinterpret_cast<float*>(smem + 16384);

    #pragma unroll
    for (int ph = 0; ph < 2; ++ph) {
        int c = ph ? (31 - cp) : cp;
        int q0 = c * 64;
        int qw = q0 + qsub * 32;
        int qrow = qw + l31;

        short8 qf[4];
        #pragma unroll
        for (int cc = 0; cc < 4; ++cc)
            qf[cc] = ld_frag(Qg4, (size_t)qrow * 8 + cc * 2 + hi);

        f32x16 oacc0 = {}, oacc1 = {};
        float l = 0.f;
        int nk = c + 1;
        int nr = (nk + 1) >> 1;          // 2-tile rounds

        auto stage2 = [&](int rd, int b) {
            char* base = smem + b * 32768;
            #pragma unroll
            for (int sub = 0; sub < 2; ++sub) {
                int kt = 2 * rd + sub;
                if (kt < nk) {
                    int kn = kt * 64;
                    #pragma unroll
                    for (int i = 0; i < 2; ++i) {
                        gload_lds16(Kg + (size_t)(kn + sr[i]) * 64 + sj[i],
                                    base + sub * 8192 + (i * 256 + w * 64) * 16);
                        gload_lds16(Vg + (size_t)sr[i] * S + kn + sj[i],
                                    base + 16384 + sub * 8192 + (i * 256 + w * 64) * 16);
                    }
                }
            }
        };

        stage2(0, 0);
        __syncthreads();
        int cur = 0;

        for (int rd = 0; rd < nr; ++rd) {
            bool staged = false;
            #pragma unroll
            for (int sub = 0; sub < 2; ++sub) {
                int kt = 2 * rd + sub;
                int kvbase = kt * 64 + kvh * 32;
                bool active = (kt < nk) && (kvbase <= qw + 31);
                short8 ka[4], va[4];
                if (active) {
                    const char* Kt = smem + cur * 32768 + sub * 8192;
                    const char* Vt = smem + cur * 32768 + 16384 + sub * 8192;
                    int r = kvh * 32 + l31;
                    #pragma unroll
                    for (int cc = 0; cc < 4; ++cc)
                        ka[cc] = __builtin_bit_cast(short8, *reinterpret_cast<const uint4*>(
                            Kt + r * 128 + (((2 * cc + hi) ^ (r & 7)) * 16)));
                    #pragma unroll
                    for (int t = 0; t < 2; ++t) {
                        va[t] = __builtin_bit_cast(short8, *reinterpret_cast<const uint4*>(
                            Vt + l31 * 128 + (((kvh * 4 + 2 * t + hi) ^ (l31 & 7)) * 16)));
                        va[2 + t] = __builtin_bit_cast(short8, *reinterpret_cast<const uint4*>(
                            Vt + (32 + l31) * 128 + (((kvh * 4 + 2 * t + hi) ^ ((32 + l31) & 7)) * 16)));
                    }
                }
                if (!staged) {
                    if (rd + 1 < nr) stage2(rd + 1, cur ^ 1);
                    staged = true;
                }
                if (active) {
                    f32x16 s = {};
                    __builtin_amdgcn_s_setprio(1);
                    #pragma unroll
                    for (int cc = 0; cc < 4; ++cc)
                        s = __builtin_amdgcn_mfma_f32_32x32x16_bf16(ka[cc], qf[cc], s, 0, 0, 0);
                    __builtin_amdgcn_s_setprio(0);

                    if (kvbase + 31 > qw) {
                        #pragma unroll
                        for (int r = 0; r < 16; ++r) {
                            int kva = kvbase + (r & 3) + 8 * (r >> 2) + 4 * hi;
                            s[r] = (kva <= qrow) ? s[r] : -1e30f;
                        }
                    }
                    #pragma unroll
                    for (int r = 0; r < 16; ++r) s[r] = exp2f(s[r]);
                    float rp0 = ((s[0] + s[4]) + (s[8] + s[12])) + ((s[1] + s[5]) + (s[9] + s[13]));
                    float rp1 = ((s[2] + s[6]) + (s[10] + s[14])) + ((s[3] + s[7]) + (s[11] + s[15]));
                    float rs = rp0 + rp1;
                    rs += __shfl_xor(rs, 32);
                    l += rs;

                    unsigned wd[8];
                    #pragma unroll
                    for (int i = 0; i < 8; ++i) wd[i] = cvt_pk_bf16(s[2 * i], s[2 * i + 1]);
                    unsigned e0 = (unsigned)__shfl_xor((int)(hi ? wd[0] : wd[2]), 32);
                    unsigned e1 = (unsigned)__shfl_xor((int)(hi ? wd[1] : wd[3]), 32);
                    unsigned e2 = (unsigned)__shfl_xor((int)(hi ? wd[4] : wd[6]), 32);
                    unsigned e3 = (unsigned)__shfl_xor((int)(hi ? wd[5] : wd[7]), 32);
                    uint4 p0 = hi ? uint4{e0, e1, wd[2], wd[3]} : uint4{wd[0], wd[1], e0, e1};
                    uint4 p1 = hi ? uint4{e2, e3, wd[6], wd[7]} : uint4{wd[4], wd[5], e2, e3};
                    short8 pb0 = __builtin_bit_cast(short8, p0);
                    short8 pb1 = __builtin_bit_cast(short8, p1);

                    __builtin_amdgcn_s_setprio(1);
                    oacc0 = __builtin_amdgcn_mfma_f32_32x32x16_bf16(va[0], pb0, oacc0, 0, 0, 0);
                    oacc0 = __builtin_amdgcn_mfma_f32_32x32x16_bf16(va[1], pb1, oacc0, 0, 0, 0);
                    oacc1 = __builtin_amdgcn_mfma_f32_32x32x16_bf16(va[2], pb0, oacc1, 0, 0, 0);
                    oacc1 = __builtin_amdgcn_mfma_f32_32x32x16_bf16(va[3], pb1, oacc1, 0, 0, 0);
                    __builtin_amdgcn_s_setprio(0);
                }
            }
            __syncthreads();
            cur ^= 1;
        }

        if (kvh) {
            #pragma unroll
            for (int r = 0; r < 16; ++r) {
                mo[(r * 2 + qsub) * 64 + lane]        = oacc0[r];
                mo[((16 + r) * 2 + qsub) * 64 + lane] = oacc1[r];
            }
            ml[qsub * 64 + lane] = l;
        }
        __syncthreads();
        if (!kvh) {
            l += ml[qsub * 64 + lane];
            float invl = 1.f / l;
            size_t orow = ((size_t)((hh >> 4) * 2048 + qrow)) * 1024 + (hh & 15) * 64;
            #pragma unroll
            for (int du = 0; du < 2; ++du) {
                const f32x16& oa = du ? oacc1 : oacc0;
                #pragma unroll
                for (int gq = 0; gq < 4; ++gq) {
                    ushort4 o;
                    #pragma unroll
                    for (int e = 0; e < 4; ++e) {
                        int r = 4 * gq + e;
                        float v = (oa[r] + mo[((du * 16 + r) * 2 + qsub) * 64 + lane]) * invl;
                        ((unsigned short*)&o)[e] = f2bf(v);
                    }
                    int d = du * 32 + 4 * hi + 8 * gq;
                    *reinterpret_cast<ushort4*>(Oattn + orow + d) = o;
                }
            }
        }
        __syncthreads();   // smem readers done before next phase restages
    }
}

extern "C" void kernel_launch(void* const* d_in, const int* in_sizes, int n_in,
                              void* d_out, int out_size, void* d_ws, size_t ws_size,
                              hipStream_t stream) {
    const float* x    = (const float*)d_in[0];   // [2,2048,1024]
    const float* wqkv = (const float*)d_in[1];   // [1024,3072]
    const float* wout = (const float*)d_in[2];   // [1024,1024]

    char* ws = (char*)d_ws;
    unsigned short* xb    = (unsigned short*)(ws);                       // 8 MB
    unsigned short* wqkvT = (unsigned short*)(ws + (8ull  << 20));       // 6 MB
    unsigned short* woutT = (unsigned short*)(ws + (14ull << 20));       // 2 MB
    unsigned short* Qb    = (unsigned short*)(ws + (40ull << 20));       // 8 MB
    unsigned short* Kb    = (unsigned short*)(ws + (48ull << 20));       // 8 MB
    unsigned short* VT    = (unsigned short*)(ws + (56ull << 20));       // 8 MB
    unsigned short* Oat   = (unsigned short*)(ws + (64ull << 20));       // 8 MB
    float* cosT           = (float*)(ws + (72ull << 20));                // 256 KB
    float* sinT           = (float*)(ws + (72ull << 20) + (256u << 10)); // 256 KB

    prep_kernel<<<3328, 256, 0, stream>>>(x, xb, wqkv, wqkvT, wout, woutT, cosT, sinT);
    gemm_qkv_rope_kernel<<<dim3(24, 32), 256, 0, stream>>>(xb, wqkvT, cosT, sinT, Qb, Kb, VT);
    flash_attn_kernel<<<512, 256, 0, stream>>>(Qb, Kb, VT, Oat);
    gemm_out_kernel<<<dim3(16, 32), 256, 0, stream>>>(Oat, woutT, (float*)d_out);
}